// Round 1
// baseline (110.623 us; speedup 1.0000x reference)
//
#include <hip/hip_runtime.h>
#include <math.h>

// ThrusterLag: y[k] = a*y[k-1] + (1-a)*tanh(2*deadzone((u-7.5)/2.5)), y[-1]=u_nl[0]
// a = exp(-DT/tau), tau = softplus(tau_param) + TAU_MIN, per channel.
// Shapes: u_seq (512, 8192, 8) f32; tau_param (8,) f32; out (512, 8192, 8) f32.

constexpr int kB    = 512;
constexpr int kL    = 8192;
constexpr int kC    = 8;
constexpr int kSeg  = 64;            // k-steps per thread segment
constexpr int kNSeg = kL / kSeg;     // 128 segments per sequence

constexpr float kDT      = 0.01f;
constexpr float kTauMin  = 0.01f;

__device__ __forceinline__ float softplus_f(float p) {
    return fmaxf(p, 0.0f) + log1pf(__expf(-fabsf(p)));
}

// nonlinearity: tanh(2 * deadzone((u - 7.5)/2.5))
__device__ __forceinline__ float u_nl(float u) {
    float uu = (u - 7.5f) * 0.4f;
    float ud = copysignf(fmaxf(fabsf(uu) - 0.05f, 0.0f), uu);
    // tanh(2*ud) = (e^{4*ud} - 1) / (e^{4*ud} + 1); 4*ud in [-7.6, 7.6], no overflow
    float e = __expf(4.0f * ud);
    return (e - 1.0f) * __builtin_amdgcn_rcpf(e + 1.0f);
}

__device__ __forceinline__ void load_coeffs(const float* __restrict__ tp,
                                            float* a, float* oma) {
    #pragma unroll
    for (int c = 0; c < kC; ++c) {
        float tau = softplus_f(tp[c]) + kTauMin;
        a[c]   = __expf(-kDT / tau);
        oma[c] = 1.0f - a[c];
    }
}

// Pass A: per (b, segment) thread computes local scan value with zero carry-in
// for all 8 channels. Lbuf[(b*kNSeg + s)*8 + c]
__global__ __launch_bounds__(256) void passA(const float* __restrict__ u,
                                             const float* __restrict__ tp,
                                             float* __restrict__ Lbuf) {
    int t = blockIdx.x * 256 + threadIdx.x;       // [0, kB*kNSeg)
    int b = t >> 7;                                // / kNSeg (=128)
    int s = t & (kNSeg - 1);

    float a[kC], oma[kC], acc[kC];
    load_coeffs(tp, a, oma);
    #pragma unroll
    for (int c = 0; c < kC; ++c) acc[c] = 0.0f;

    const float4* src = (const float4*)(u + ((size_t)b * kL + (size_t)s * kSeg) * kC);
    #pragma unroll 4
    for (int i = 0; i < kSeg; ++i) {
        float4 x0 = src[2 * i];
        float4 x1 = src[2 * i + 1];
        float v[kC] = {x0.x, x0.y, x0.z, x0.w, x1.x, x1.y, x1.z, x1.w};
        #pragma unroll
        for (int c = 0; c < kC; ++c)
            acc[c] = a[c] * acc[c] + oma[c] * u_nl(v[c]);
    }

    float4* lb = (float4*)(Lbuf + (size_t)t * kC);
    lb[0] = make_float4(acc[0], acc[1], acc[2], acc[3]);
    lb[1] = make_float4(acc[4], acc[5], acc[6], acc[7]);
}

// Pass B: per (b,c) thread scans the 128 segment summaries into carries.
// Cbuf[(b*kNSeg + s)*8 + c] = carry INTO segment s (= y[s*kSeg - 1], y[-1]=u_nl[0]).
__global__ __launch_bounds__(256) void passB(const float* __restrict__ u,
                                             const float* __restrict__ tp,
                                             const float* __restrict__ Lbuf,
                                             float* __restrict__ Cbuf) {
    int t = blockIdx.x * 256 + threadIdx.x;       // [0, kB*kC)
    int b = t >> 3;
    int c = t & (kC - 1);

    float tau = softplus_f(tp[c]) + kTauMin;
    float A = __expf(-kDT * (float)kSeg / tau);   // a^kSeg

    float carry = u_nl(u[(size_t)b * kL * kC + c]);   // y[-1] = u_nl[b,0,c]
    Cbuf[((size_t)b * kNSeg) * kC + c] = carry;

    #pragma unroll 8
    for (int s = 0; s < kNSeg - 1; ++s) {
        carry = A * carry + Lbuf[((size_t)b * kNSeg + s) * kC + c];
        Cbuf[((size_t)b * kNSeg + s + 1) * kC + c] = carry;
    }
}

// Pass C: per (b, segment) thread: seed with carry, recompute nonlinearity, emit y.
__global__ __launch_bounds__(256) void passC(const float* __restrict__ u,
                                             const float* __restrict__ tp,
                                             const float* __restrict__ Cbuf,
                                             float* __restrict__ out) {
    int t = blockIdx.x * 256 + threadIdx.x;       // [0, kB*kNSeg)
    int b = t >> 7;
    int s = t & (kNSeg - 1);

    float a[kC], oma[kC], y[kC];
    load_coeffs(tp, a, oma);

    const float4* cb = (const float4*)(Cbuf + (size_t)t * kC);
    float4 c0 = cb[0], c1 = cb[1];
    y[0] = c0.x; y[1] = c0.y; y[2] = c0.z; y[3] = c0.w;
    y[4] = c1.x; y[5] = c1.y; y[6] = c1.z; y[7] = c1.w;

    size_t off = ((size_t)b * kL + (size_t)s * kSeg) * kC;
    const float4* src = (const float4*)(u + off);
    float4*       dst = (float4*)(out + off);

    #pragma unroll 4
    for (int i = 0; i < kSeg; ++i) {
        float4 x0 = src[2 * i];
        float4 x1 = src[2 * i + 1];
        float v[kC] = {x0.x, x0.y, x0.z, x0.w, x1.x, x1.y, x1.z, x1.w};
        #pragma unroll
        for (int c = 0; c < kC; ++c)
            y[c] = a[c] * y[c] + oma[c] * u_nl(v[c]);
        dst[2 * i]     = make_float4(y[0], y[1], y[2], y[3]);
        dst[2 * i + 1] = make_float4(y[4], y[5], y[6], y[7]);
    }
}

extern "C" void kernel_launch(void* const* d_in, const int* in_sizes, int n_in,
                              void* d_out, int out_size, void* d_ws, size_t ws_size,
                              hipStream_t stream) {
    const float* u  = (const float*)d_in[0];
    const float* tp = (const float*)d_in[1];
    float* out = (float*)d_out;

    float* Lbuf = (float*)d_ws;                          // kB*kNSeg*kC floats = 2 MB
    float* Cbuf = Lbuf + (size_t)kB * kNSeg * kC;        // another 2 MB

    passA<<<(kB * kNSeg) / 256, 256, 0, stream>>>(u, tp, Lbuf);
    passB<<<(kB * kC) / 256,   256, 0, stream>>>(u, tp, Lbuf, Cbuf);
    passC<<<(kB * kNSeg) / 256, 256, 0, stream>>>(u, tp, Cbuf, out);
}